// Round 1
// baseline (485.657 us; speedup 1.0000x reference)
//
#include <hip/hip_runtime.h>
#include <hip/hip_bf16.h>

// LinearAttention fused pipeline for MI355X (gfx950), bf16 MFMA.
// B=8, C=512, L=8192, H=8, DH=64, HID=512, M1=3*HID=1536.

typedef short short8 __attribute__((ext_vector_type(8)));
typedef short short4v __attribute__((ext_vector_type(4)));
typedef float f32x4 __attribute__((ext_vector_type(4)));
typedef unsigned short ushort;

#define SQRT512 22.627416997969522f

__device__ __forceinline__ ushort f2bf(float f){
  union{float f; unsigned u;} v; v.f = f;
  unsigned r = v.u + 0x7fffu + ((v.u >> 16) & 1u);
  return (ushort)(r >> 16);
}

// async global->LDS, 16B per lane; lds dest must be wave-uniform base (HW adds lane*16)
__device__ __forceinline__ void gload16(const void* g, void* l){
  __builtin_amdgcn_global_load_lds(
      (const __attribute__((address_space(1))) unsigned int*)(unsigned long long)g,
      (__attribute__((address_space(3))) unsigned int*)(unsigned int)(unsigned long long)l,
      16, 0, 0);
}

// ---------------- K0b: W1[o][c] = w_qkv[o][c] * g1[c] * sqrt(512)  (bf16) ----------------
__global__ void k_prep_w1(const float* __restrict__ wqkv, const float* __restrict__ g1,
                          ushort* __restrict__ W1){
  int i = blockIdx.x * 256 + threadIdx.x;   // 1536*512 exact
  int c = i & 511;
  W1[i] = f2bf(wqkv[i] * g1[c] * SQRT512);
}

// ---------------- K0: transpose x -> Xt[b][l][c] bf16, and invnorm[b][l] = 1/max(||x_col||,1e-12)
__global__ __launch_bounds__(256) void k_xt(const float* __restrict__ x,
                                            ushort* __restrict__ Xt,
                                            float* __restrict__ invnorm){
  __shared__ __align__(16) ushort tile[64*132]; // 64 l-rows x 128 c, pitch 132
  __shared__ float ssq[4][64];
  int b = blockIdx.y, lb = blockIdx.x;
  int t = threadIdx.x, lane = t & 63, crow = t >> 6;
  const float* xb = x + ((size_t)b*512)*8192 + (size_t)lb*64;
  float acc = 0.f;
  for(int c0 = 0; c0 < 512; c0 += 128){
    __syncthreads();
    for(int cc = crow; cc < 128; cc += 4){
      float v = xb[(size_t)(c0+cc)*8192 + lane];
      acc += v*v;
      tile[lane*132 + cc] = f2bf(v);
    }
    __syncthreads();
    ushort* dst = Xt + ((size_t)(b*8192 + lb*64))*512 + c0;
    int ch = t & 31;
    for(int r = t >> 5; r < 64; r += 8){
      short4v vv = *(const short4v*)&tile[r*132 + ch*4];
      *(short4v*)(dst + (size_t)r*512 + ch*4) = vv;
    }
  }
  ssq[crow][lane] = acc;
  __syncthreads();
  if(t < 64){
    float s = ssq[0][t] + ssq[1][t] + ssq[2][t] + ssq[3][t];
    invnorm[b*8192 + lb*64 + t] = 1.f / fmaxf(sqrtf(s), 1e-12f);
  }
}

// ---------------- K1: QKV GEMM (1536x512 @ 512xL per batch) with fused epilogues ----------
// tile 128x128, BK=64, 4 waves. A=W1 [o][c], B=Xt [l][c] (both contiguous-K).
// LDS tiles stored as 16B chunks [g][row] with g = klocal/8 (conflict-free b128 frag reads).
__global__ __launch_bounds__(256,3) void k_qkv(
    const ushort* __restrict__ W1, const ushort* __restrict__ Xt,
    const float* __restrict__ invnorm,
    ushort* __restrict__ Qt, ushort* __restrict__ EK, ushort* __restrict__ V,
    float* __restrict__ kpart){
  __shared__ __align__(16) union {
    struct { ushort A[8192]; ushort B[8192]; } m;              // 16KiB + 16KiB
    struct { ushort t[128*136]; float ksum[128]; } kv;          // epilogue staging
  } S;
  int bid = blockIdx.x;                           // 6144
  int wg = (bid & 7)*768 + (bid >> 3);            // XCD-contiguous: each XCD gets one batch
  int r = wg % 12; int ct = (wg/12) & 63; int b = wg / 768;
  int t = threadIdx.x, lane = t & 63, w = t >> 6;
  int wr = w >> 1, wc = w & 1;
  f32x4 acc[4][4] = {};
  const ushort* Arow = W1 + (size_t)(r*128)*512;
  const ushort* Brow = Xt + ((size_t)(b*8192 + ct*128))*512;
  for(int ks = 0; ks < 8; ++ks){
    int cbase = ks*64;
#pragma unroll
    for(int j = 0; j < 4; ++j){
      int m = w*4 + j; int g = m >> 1; int row = (m & 1)*64 + lane;
      gload16(Arow + (size_t)row*512 + cbase + g*8, &S.m.A[m*512]);
      gload16(Brow + (size_t)row*512 + cbase + g*8, &S.m.B[m*512]);
    }
    __syncthreads();
#pragma unroll
    for(int kk = 0; kk < 2; ++kk){
      int g = kk*4 + (lane >> 4);
      short8 af[4], bf[4];
#pragma unroll
      for(int m4 = 0; m4 < 4; ++m4)
        af[m4] = *(const short8*)&S.m.A[(g*128 + wr*64 + m4*16 + (lane & 15))*8];
#pragma unroll
      for(int n4 = 0; n4 < 4; ++n4)
        bf[n4] = *(const short8*)&S.m.B[(g*128 + wc*64 + n4*16 + (lane & 15))*8];
#pragma unroll
      for(int m4 = 0; m4 < 4; ++m4)
#pragma unroll
        for(int n4 = 0; n4 < 4; ++n4)
          acc[m4][n4] = __builtin_amdgcn_mfma_f32_16x16x32_bf16(af[m4], bf[n4], acc[m4][n4], 0,0,0);
    }
    __syncthreads();
  }
  // column scales (1/||x_col||)
  float cs[4];
  const float* invb = invnorm + b*8192 + ct*128;
#pragma unroll
  for(int n4 = 0; n4 < 4; ++n4) cs[n4] = invb[wc*64 + n4*16 + (lane & 15)];

  if(r < 4){
    // ---- Q: softmax over the 64 dh-rows of this wave's head, in registers ----
    float mx[4] = {-3e38f,-3e38f,-3e38f,-3e38f};
#pragma unroll
    for(int m4 = 0; m4 < 4; ++m4)
#pragma unroll
      for(int n4 = 0; n4 < 4; ++n4)
#pragma unroll
        for(int j = 0; j < 4; ++j){
          float v = acc[m4][n4][j]*cs[n4];
          acc[m4][n4][j] = v;
          mx[n4] = fmaxf(mx[n4], v);
        }
#pragma unroll
    for(int n4 = 0; n4 < 4; ++n4){
      mx[n4] = fmaxf(mx[n4], __shfl_xor(mx[n4], 16));
      mx[n4] = fmaxf(mx[n4], __shfl_xor(mx[n4], 32));
    }
    float sm[4] = {0.f,0.f,0.f,0.f};
#pragma unroll
    for(int m4 = 0; m4 < 4; ++m4)
#pragma unroll
      for(int n4 = 0; n4 < 4; ++n4)
#pragma unroll
        for(int j = 0; j < 4; ++j){
          float e = __expf(acc[m4][n4][j] - mx[n4]);
          acc[m4][n4][j] = e;
          sm[n4] += e;
        }
    float inv[4];
#pragma unroll
    for(int n4 = 0; n4 < 4; ++n4){
      sm[n4] += __shfl_xor(sm[n4], 16);
      sm[n4] += __shfl_xor(sm[n4], 32);
      inv[n4] = 0.125f / sm[n4];             // * dh^-0.5
    }
    // write transposed: Qt[b][l][hid]
#pragma unroll
    for(int n4 = 0; n4 < 4; ++n4){
      int col = ct*128 + wc*64 + n4*16 + (lane & 15);
      ushort* dst = Qt + ((size_t)(b*8192 + col))*512 + r*128 + wr*64 + (lane >> 4)*4;
#pragma unroll
      for(int m4 = 0; m4 < 4; ++m4){
        short4v p;
#pragma unroll
        for(int j = 0; j < 4; ++j) p[j] = (short)f2bf(acc[m4][n4][j]*inv[n4]);
        *(short4v*)(dst + m4*16) = p;
      }
    }
  } else {
    // ---- K (exp + partial row sums) and V paths, staged through LDS for coalesced stores ----
    bool isK = (r < 8);
    int hidbase = isK ? (r-4)*128 : (r-8)*128;
    if(isK && t < 128) S.kv.ksum[t] = 0.f;
    __syncthreads();
#pragma unroll
    for(int m4 = 0; m4 < 4; ++m4)
#pragma unroll
      for(int j = 0; j < 4; ++j){
        int row = wr*64 + m4*16 + (lane >> 4)*4 + j;
        float rs = 0.f;
#pragma unroll
        for(int n4 = 0; n4 < 4; ++n4){
          int col = wc*64 + n4*16 + (lane & 15);
          float val = acc[m4][n4][j]*cs[n4];
          if(isK){ float e = __expf(val); S.kv.t[row*136 + col] = f2bf(e); rs += e; }
          else   { S.kv.t[row*136 + col] = f2bf(val); }
        }
        if(isK) atomicAdd(&S.kv.ksum[row], rs);
      }
    __syncthreads();
    ushort* dstbase = (isK ? EK : V) + ((size_t)(b*512 + hidbase))*8192 + ct*128;
    int ch = t & 15;
    for(int rr = t >> 4; rr < 128; rr += 16){
      short8 vv = *(const short8*)&S.kv.t[rr*136 + ch*8];
      *(short8*)(dstbase + (size_t)rr*8192 + ch*8) = vv;
    }
    if(isK && t < 128)
      kpart[(size_t)ct*4096 + b*512 + hidbase + t] = S.kv.ksum[t];
  }
}

// ---------------- K2: invZ[row] = 1 / sum_ct kpart[ct][row]  (row = b*512 + h*64 + d) -------
__global__ void k_invz(const float* __restrict__ kpart, float* __restrict__ invZ){
  int row = blockIdx.x*256 + threadIdx.x;   // 4096 exact
  float s = 0.f;
  for(int c = 0; c < 64; ++c) s += kpart[(size_t)c*4096 + row];
  invZ[row] = 1.f / s;
}

// ---------------- K3: ctx partials: EXPK(64xL) @ V(64xL)^T, split-K=16 --------------------
__global__ __launch_bounds__(256,4) void k_ctx(const ushort* __restrict__ EK,
                                               const ushort* __restrict__ V,
                                               float* __restrict__ ctxp){
  __shared__ __align__(16) ushort A[4096];   // 8 g x 64 rows x 16B
  __shared__ __align__(16) ushort Bs[4096];
  int bid = blockIdx.x;                      // 1024 = 64 bh * 16 splits
  int split = bid & 15, bh = bid >> 4;
  int t = threadIdx.x, lane = t & 63, w = t >> 6;
  const ushort* Abase = EK + (size_t)bh*64*8192;
  const ushort* Bbase = V  + (size_t)bh*64*8192;
  f32x4 acc[4] = {};
  for(int ks = 0; ks < 8; ++ks){
    int n0 = split*512 + ks*64;
#pragma unroll
    for(int j = 0; j < 2; ++j){
      int g = w*2 + j;
      gload16(Abase + (size_t)lane*8192 + n0 + g*8, &A[g*512]);
      gload16(Bbase + (size_t)lane*8192 + n0 + g*8, &Bs[g*512]);
    }
    __syncthreads();
#pragma unroll
    for(int kk = 0; kk < 2; ++kk){
      int g = kk*4 + (lane >> 4);
      short8 af = *(const short8*)&A[(g*64 + w*16 + (lane & 15))*8];
#pragma unroll
      for(int n4 = 0; n4 < 4; ++n4){
        short8 bf = *(const short8*)&Bs[(g*64 + n4*16 + (lane & 15))*8];
        acc[n4] = __builtin_amdgcn_mfma_f32_16x16x32_bf16(af, bf, acc[n4], 0,0,0);
      }
    }
    __syncthreads();
  }
  float* dst = ctxp + ((size_t)(bh*16 + split))*4096;
#pragma unroll
  for(int n4 = 0; n4 < 4; ++n4)
#pragma unroll
    for(int j = 0; j < 4; ++j){
      int d = w*16 + (lane >> 4)*4 + j, e = n4*16 + (lane & 15);
      dst[d*64 + e] = acc[n4][j];
    }
}

// ---------------- K3b: reduce ctx partials, scale by invZ, fold W_out: M2_b ---------------
// M2[b][o][h*64+d] = sum_e Wout[o][h*64+e] * (ctx[d][e]*invZ[d])
__global__ void k_m2(const float* __restrict__ ctxp, const float* __restrict__ invZ,
                     const float* __restrict__ Wout, ushort* __restrict__ M2){
  __shared__ __align__(16) ushort ctxl[4096]; // chunked [g=e/8][d][8]
  int bh = blockIdx.x, b = bh >> 3, h = bh & 7;
  int t = threadIdx.x, lane = t & 63, w = t >> 6;  // 512 threads, 8 waves
  for(int i = t; i < 4096; i += 512){
    float s = 0.f;
    for(int sp = 0; sp < 16; ++sp) s += ctxp[((size_t)(bh*16 + sp))*4096 + i];
    int d = i >> 6, e = i & 63;
    s *= invZ[bh*64 + d];
    ctxl[(e >> 3)*512 + d*8 + (e & 7)] = f2bf(s);
  }
  __syncthreads();
  f32x4 acc[4][4] = {};
#pragma unroll
  for(int kk = 0; kk < 2; ++kk){
    int g = kk*4 + (lane >> 4);
    short8 bf[4];
#pragma unroll
    for(int n4 = 0; n4 < 4; ++n4)
      bf[n4] = *(const short8*)&ctxl[g*512 + (n4*16 + (lane & 15))*8];
    int e0 = (lane >> 4)*8 + kk*32;
#pragma unroll
    for(int m4 = 0; m4 < 4; ++m4){
      int o = w*64 + m4*16 + (lane & 15);
      const float* wp = Wout + (size_t)o*512 + h*64 + e0;
      float4 w0 = *(const float4*)(wp);
      float4 w1 = *(const float4*)(wp + 4);
      short8 af;
      af[0]=(short)f2bf(w0.x); af[1]=(short)f2bf(w0.y); af[2]=(short)f2bf(w0.z); af[3]=(short)f2bf(w0.w);
      af[4]=(short)f2bf(w1.x); af[5]=(short)f2bf(w1.y); af[6]=(short)f2bf(w1.z); af[7]=(short)f2bf(w1.w);
#pragma unroll
      for(int n4 = 0; n4 < 4; ++n4)
        acc[m4][n4] = __builtin_amdgcn_mfma_f32_16x16x32_bf16(af, bf[n4], acc[m4][n4], 0,0,0);
    }
  }
  ushort* dst = M2 + (size_t)b*512*512 + h*64;
#pragma unroll
  for(int m4 = 0; m4 < 4; ++m4)
#pragma unroll
    for(int n4 = 0; n4 < 4; ++n4)
#pragma unroll
      for(int j = 0; j < 4; ++j){
        int o = w*64 + m4*16 + (lane >> 4)*4 + j;
        int d = n4*16 + (lane & 15);
        dst[(size_t)o*512 + d] = f2bf(acc[m4][n4][j]);
      }
}

// ---------------- K4: out = rmsnorm(M2_b @ Q + b_out, g2), tall tile 512x64, K=512 --------
__global__ __launch_bounds__(512,2) void k_out(const ushort* __restrict__ M2,
                                               const ushort* __restrict__ Qt,
                                               const float* __restrict__ bout,
                                               const float* __restrict__ g2,
                                               float* __restrict__ out){
  __shared__ __align__(16) ushort A[16384];  // 4 g x 512 o x 16B = 32 KiB
  __shared__ __align__(16) ushort Bs[2048];  // 4 g x 64 l x 16B
  __shared__ float colss[64];
  __shared__ float bo[512], gg[512];
  int bid = blockIdx.x;                      // 1024
  int wg = (bid & 7)*128 + (bid >> 3);       // XCD-contiguous per batch
  int b = wg >> 7, lb = wg & 127;
  int t = threadIdx.x, lane = t & 63, w = t >> 6;  // 8 waves
  bo[t & 511] = bout[t & 511];
  gg[t & 511] = g2[t & 511];
  if(t < 64) colss[t] = 0.f;
  const ushort* Abase = M2 + (size_t)b*262144;
  const ushort* Bbase = Qt + ((size_t)(b*8192 + lb*64))*512;
  f32x4 acc[4][4] = {};
  for(int ks = 0; ks < 16; ++ks){
    int k0 = ks*32;
#pragma unroll
    for(int j = 0; j < 4; ++j){
      int m = w*4 + j; int g = m >> 3; int orow = (m & 7)*64 + lane;
      gload16(Abase + (size_t)orow*512 + k0 + g*8, &A[m*512]);
    }
    if(w < 4) gload16(Bbase + (size_t)lane*512 + k0 + w*8, &Bs[w*512]);
    __syncthreads();
    int g = lane >> 4;
    short8 bf[4];
#pragma unroll
    for(int n4 = 0; n4 < 4; ++n4)
      bf[n4] = *(const short8*)&Bs[(g*64 + n4*16 + (lane & 15))*8];
#pragma unroll
    for(int m4 = 0; m4 < 4; ++m4){
      short8 af = *(const short8*)&A[(g*512 + w*64 + m4*16 + (lane & 15))*8];
#pragma unroll
      for(int n4 = 0; n4 < 4; ++n4)
        acc[m4][n4] = __builtin_amdgcn_mfma_f32_16x16x32_bf16(af, bf[n4], acc[m4][n4], 0,0,0);
    }
    __syncthreads();
  }
  // bias + column sumsq
  float ps[4] = {0.f,0.f,0.f,0.f};
#pragma unroll
  for(int m4 = 0; m4 < 4; ++m4)
#pragma unroll
    for(int j = 0; j < 4; ++j){
      int o = w*64 + m4*16 + (lane >> 4)*4 + j;
      float bb = bo[o];
#pragma unroll
      for(int n4 = 0; n4 < 4; ++n4){
        float v = acc[m4][n4][j] + bb;
        acc[m4][n4][j] = v;
        ps[n4] += v*v;
      }
    }
#pragma unroll
  for(int n4 = 0; n4 < 4; ++n4) atomicAdd(&colss[n4*16 + (lane & 15)], ps[n4]);
  __syncthreads();
  float csc[4];
#pragma unroll
  for(int n4 = 0; n4 < 4; ++n4)
    csc[n4] = SQRT512 / fmaxf(sqrtf(colss[n4*16 + (lane & 15)]), 1e-12f);
  float* obase = out + ((size_t)b*512)*8192 + lb*64;
#pragma unroll
  for(int m4 = 0; m4 < 4; ++m4)
#pragma unroll
    for(int j = 0; j < 4; ++j){
      int o = w*64 + m4*16 + (lane >> 4)*4 + j;
      float gv = gg[o];
#pragma unroll
      for(int n4 = 0; n4 < 4; ++n4)
        obase[(size_t)o*8192 + n4*16 + (lane & 15)] = acc[m4][n4][j]*csc[n4]*gv;
    }
}

extern "C" void kernel_launch(void* const* d_in, const int* in_sizes, int n_in,
                              void* d_out, int out_size, void* d_ws, size_t ws_size,
                              hipStream_t stream){
  const float* x    = (const float*)d_in[0];
  const float* g1   = (const float*)d_in[1];
  const float* wqkv = (const float*)d_in[2];
  const float* wout = (const float*)d_in[3];
  const float* bout = (const float*)d_in[4];
  const float* g2   = (const float*)d_in[5];
  float* out = (float*)d_out;
  char* ws = (char*)d_ws;
  const size_t MB = 1024*1024;
  // ws layout (~153 MiB)
  ushort* Qt      = (ushort*)(ws);              // 64 MiB  [b][l][512]
  ushort* EK      = (ushort*)(ws + 64*MB);      // 64 MiB  [b][512][l]
  ushort* W1      = (ushort*)(ws + 128*MB);     // 1.5 MiB
  float*  invnorm = (float*) (ws + 130*MB);     // 256 KiB
  float*  kpart   = (float*) (ws + 131*MB);     // 1 MiB [64 ct][4096 rows]
  float*  invZ    = (float*) (ws + 132*MB);     // 16 KiB
  float*  ctxp    = (float*) (ws + 133*MB);     // 16 MiB [64 bh][16][64][64]
  ushort* M2      = (ushort*)(ws + 149*MB);     // 4 MiB  [b][512][512]
  // d_out doubles as scratch until k_out: Xt in first half, V in second half
  ushort* Xt = (ushort*)d_out;
  ushort* V  = (ushort*)((char*)d_out + 64*MB);

  k_prep_w1<<<3072, 256, 0, stream>>>(wqkv, g1, W1);
  k_xt<<<dim3(128, 8), 256, 0, stream>>>(x, Xt, invnorm);
  k_qkv<<<6144, 256, 0, stream>>>(W1, Xt, invnorm, Qt, EK, V, kpart);
  k_invz<<<16, 256, 0, stream>>>(kpart, invZ);
  k_ctx<<<1024, 256, 0, stream>>>(EK, V, ctxp);
  k_m2<<<64, 512, 0, stream>>>(ctxp, invZ, wout, M2);
  k_out<<<1024, 512, 0, stream>>>(M2, Qt, bout, g2, out);
}

// Round 2
// 390.990 us; speedup vs baseline: 1.2421x; 1.2421x over previous
//
#include <hip/hip_runtime.h>
#include <hip/hip_bf16.h>

// LinearAttention fused pipeline for MI355X (gfx950), bf16 MFMA.
// B=8, C=512, L=8192, H=8, DH=64, HID=512, M1=3*HID=1536.
// R1: coalesced 128B-granule staging + XOR chunk swizzle (write-side via
// pre-swizzled global src, read-side on ds_read) in k_qkv/k_ctx/k_out.

typedef short short8 __attribute__((ext_vector_type(8)));
typedef short short4v __attribute__((ext_vector_type(4)));
typedef float f32x4 __attribute__((ext_vector_type(4)));
typedef unsigned short ushort;

#define SQRT512 22.627416997969522f

__device__ __forceinline__ ushort f2bf(float f){
  union{float f; unsigned u;} v; v.f = f;
  unsigned r = v.u + 0x7fffu + ((v.u >> 16) & 1u);
  return (ushort)(r >> 16);
}

// async global->LDS, 16B per lane; lds dest is wave-uniform base (HW adds lane*16)
__device__ __forceinline__ void gload16(const void* g, void* l){
  __builtin_amdgcn_global_load_lds(
      (const __attribute__((address_space(1))) unsigned int*)(unsigned long long)g,
      (__attribute__((address_space(3))) unsigned int*)(unsigned int)(unsigned long long)l,
      16, 0, 0);
}

// ---------------- K0b: W1[o][c] = w_qkv[o][c] * g1[c] * sqrt(512)  (bf16) ----------------
__global__ void k_prep_w1(const float* __restrict__ wqkv, const float* __restrict__ g1,
                          ushort* __restrict__ W1){
  int i = blockIdx.x * 256 + threadIdx.x;   // 1536*512 exact
  int c = i & 511;
  W1[i] = f2bf(wqkv[i] * g1[c] * SQRT512);
}

// ---------------- K0: transpose x -> Xt[b][l][c] bf16, and invnorm[b][l] ------------------
__global__ __launch_bounds__(256) void k_xt(const float* __restrict__ x,
                                            ushort* __restrict__ Xt,
                                            float* __restrict__ invnorm){
  __shared__ __align__(16) ushort tile[64*132]; // 64 l-rows x 128 c, pitch 132
  __shared__ float ssq[4][64];
  int b = blockIdx.y, lb = blockIdx.x;
  int t = threadIdx.x, lane = t & 63, crow = t >> 6;
  const float* xb = x + ((size_t)b*512)*8192 + (size_t)lb*64;
  float acc = 0.f;
  for(int c0 = 0; c0 < 512; c0 += 128){
    __syncthreads();
    for(int cc = crow; cc < 128; cc += 4){
      float v = xb[(size_t)(c0+cc)*8192 + lane];
      acc += v*v;
      tile[lane*132 + cc] = f2bf(v);
    }
    __syncthreads();
    ushort* dst = Xt + ((size_t)(b*8192 + lb*64))*512 + c0;
    int ch = t & 31;
    for(int r = t >> 5; r < 64; r += 8){
      short4v vv = *(const short4v*)&tile[r*132 + ch*4];
      *(short4v*)(dst + (size_t)r*512 + ch*4) = vv;
    }
  }
  ssq[crow][lane] = acc;
  __syncthreads();
  if(t < 64){
    float s = ssq[0][t] + ssq[1][t] + ssq[2][t] + ssq[3][t];
    invnorm[b*8192 + lb*64 + t] = 1.f / fmaxf(sqrtf(s), 1e-12f);
  }
}

// ---------------- K1: QKV GEMM (1536x512 @ 512xL per batch) with fused epilogues ----------
// tile 128x128, BK=64, 4 waves. LDS tiles row-major [128][64] with chunk-XOR swizzle:
// physical 16B-chunk p at row r holds logical chunk p ^ (r&7).
__global__ __launch_bounds__(256,3) void k_qkv(
    const ushort* __restrict__ W1, const ushort* __restrict__ Xt,
    const float* __restrict__ invnorm,
    ushort* __restrict__ Qt, ushort* __restrict__ EK, ushort* __restrict__ V,
    float* __restrict__ kpart){
  __shared__ __align__(16) union {
    struct { ushort A[8192]; ushort B[8192]; } m;              // 16KiB + 16KiB
    struct { ushort t[128*136]; float ksum[128]; } kv;          // epilogue staging
  } S;
  int bid = blockIdx.x;                           // 6144
  int wg = (bid & 7)*768 + (bid >> 3);            // XCD-contiguous: each XCD gets one batch
  int r = wg % 12; int ct = (wg/12) & 63; int b = wg / 768;
  int t = threadIdx.x, lane = t & 63, w = t >> 6;
  int wr = w >> 1, wc = w & 1;
  f32x4 acc[4][4] = {};
  const ushort* Arow = W1 + (size_t)(r*128)*512;
  const ushort* Brow = Xt + ((size_t)(b*8192 + ct*128))*512;
  int rsub = lane >> 3;                 // 0..7 (row within 8-row group)
  int pc   = (lane & 7) ^ rsub;         // pre-swizzled source chunk
  for(int ks = 0; ks < 8; ++ks){
    int goff = ks*64 + pc*8;
#pragma unroll
    for(int j = 0; j < 4; ++j){
      int m = w*4 + j;                  // 0..15, 8 rows each
      gload16(Arow + (size_t)(m*8 + rsub)*512 + goff, &S.m.A[m*512]);
      gload16(Brow + (size_t)(m*8 + rsub)*512 + goff, &S.m.B[m*512]);
    }
    __syncthreads();
#pragma unroll
    for(int kk = 0; kk < 2; ++kk){
      int g = kk*4 + (lane >> 4);
      short8 af[4], bf[4];
#pragma unroll
      for(int m4 = 0; m4 < 4; ++m4){
        int ra = wr*64 + m4*16 + (lane & 15);
        af[m4] = *(const short8*)&S.m.A[ra*64 + (g ^ (ra & 7))*8];
      }
#pragma unroll
      for(int n4 = 0; n4 < 4; ++n4){
        int rb = wc*64 + n4*16 + (lane & 15);
        bf[n4] = *(const short8*)&S.m.B[rb*64 + (g ^ (rb & 7))*8];
      }
#pragma unroll
      for(int m4 = 0; m4 < 4; ++m4)
#pragma unroll
        for(int n4 = 0; n4 < 4; ++n4)
          acc[m4][n4] = __builtin_amdgcn_mfma_f32_16x16x32_bf16(af[m4], bf[n4], acc[m4][n4], 0,0,0);
    }
    __syncthreads();
  }
  // column scales (1/||x_col||)
  float cs[4];
  const float* invb = invnorm + b*8192 + ct*128;
#pragma unroll
  for(int n4 = 0; n4 < 4; ++n4) cs[n4] = invb[wc*64 + n4*16 + (lane & 15)];

  if(r < 4){
    // ---- Q: softmax over the 64 dh-rows of this wave's head, in registers ----
    float mx[4] = {-3e38f,-3e38f,-3e38f,-3e38f};
#pragma unroll
    for(int m4 = 0; m4 < 4; ++m4)
#pragma unroll
      for(int n4 = 0; n4 < 4; ++n4)
#pragma unroll
        for(int j = 0; j < 4; ++j){
          float v = acc[m4][n4][j]*cs[n4];
          acc[m4][n4][j] = v;
          mx[n4] = fmaxf(mx[n4], v);
        }
#pragma unroll
    for(int n4 = 0; n4 < 4; ++n4){
      mx[n4] = fmaxf(mx[n4], __shfl_xor(mx[n4], 16));
      mx[n4] = fmaxf(mx[n4], __shfl_xor(mx[n4], 32));
    }
    float sm[4] = {0.f,0.f,0.f,0.f};
#pragma unroll
    for(int m4 = 0; m4 < 4; ++m4)
#pragma unroll
      for(int n4 = 0; n4 < 4; ++n4)
#pragma unroll
        for(int j = 0; j < 4; ++j){
          float e = __expf(acc[m4][n4][j] - mx[n4]);
          acc[m4][n4][j] = e;
          sm[n4] += e;
        }
    float inv[4];
#pragma unroll
    for(int n4 = 0; n4 < 4; ++n4){
      sm[n4] += __shfl_xor(sm[n4], 16);
      sm[n4] += __shfl_xor(sm[n4], 32);
      inv[n4] = 0.125f / sm[n4];             // * dh^-0.5
    }
    // write transposed: Qt[b][l][hid]
#pragma unroll
    for(int n4 = 0; n4 < 4; ++n4){
      int col = ct*128 + wc*64 + n4*16 + (lane & 15);
      ushort* dst = Qt + ((size_t)(b*8192 + col))*512 + r*128 + wr*64 + (lane >> 4)*4;
#pragma unroll
      for(int m4 = 0; m4 < 4; ++m4){
        short4v p;
#pragma unroll
        for(int j = 0; j < 4; ++j) p[j] = (short)f2bf(acc[m4][n4][j]*inv[n4]);
        *(short4v*)(dst + m4*16) = p;
      }
    }
  } else {
    // ---- K (exp + partial row sums) and V paths, staged through LDS for coalesced stores ----
    bool isK = (r < 8);
    int hidbase = isK ? (r-4)*128 : (r-8)*128;
    if(isK && t < 128) S.kv.ksum[t] = 0.f;
    __syncthreads();
#pragma unroll
    for(int m4 = 0; m4 < 4; ++m4)
#pragma unroll
      for(int j = 0; j < 4; ++j){
        int row = wr*64 + m4*16 + (lane >> 4)*4 + j;
        float rs = 0.f;
#pragma unroll
        for(int n4 = 0; n4 < 4; ++n4){
          int col = wc*64 + n4*16 + (lane & 15);
          float val = acc[m4][n4][j]*cs[n4];
          if(isK){ float e = __expf(val); S.kv.t[row*136 + col] = f2bf(e); rs += e; }
          else   { S.kv.t[row*136 + col] = f2bf(val); }
        }
        if(isK) atomicAdd(&S.kv.ksum[row], rs);
      }
    __syncthreads();
    ushort* dstbase = (isK ? EK : V) + ((size_t)(b*512 + hidbase))*8192 + ct*128;
    int ch = t & 15;
    for(int rr = t >> 4; rr < 128; rr += 16){
      short8 vv = *(const short8*)&S.kv.t[rr*136 + ch*8];
      *(short8*)(dstbase + (size_t)rr*8192 + ch*8) = vv;
    }
    if(isK && t < 128)
      kpart[(size_t)ct*4096 + b*512 + hidbase + t] = S.kv.ksum[t];
  }
}

// ---------------- K2: invZ[row] = 1 / sum_ct kpart[ct][row] ------------------------------
__global__ void k_invz(const float* __restrict__ kpart, float* __restrict__ invZ){
  int row = blockIdx.x*256 + threadIdx.x;   // 4096 exact
  float s = 0.f;
  for(int c = 0; c < 64; ++c) s += kpart[(size_t)c*4096 + row];
  invZ[row] = 1.f / s;
}

// ---------------- K3: ctx partials: EXPK(64xL) @ V(64xL)^T, split-K=16 --------------------
// LDS tiles row-major [64][64] with chunk-XOR swizzle (same scheme as k_qkv).
__global__ __launch_bounds__(256,4) void k_ctx(const ushort* __restrict__ EK,
                                               const ushort* __restrict__ V,
                                               float* __restrict__ ctxp){
  __shared__ __align__(16) ushort A[4096];   // 64 rows x 64 elems
  __shared__ __align__(16) ushort Bs[4096];
  int bid = blockIdx.x;                      // 1024 = 64 bh * 16 splits
  int split = bid & 15, bh = bid >> 4;
  int t = threadIdx.x, lane = t & 63, w = t >> 6;
  const ushort* Abase = EK + (size_t)bh*64*8192;
  const ushort* Bbase = V  + (size_t)bh*64*8192;
  int rsub = lane >> 3;
  int pc   = (lane & 7) ^ rsub;
  f32x4 acc[4] = {};
  for(int ks = 0; ks < 8; ++ks){
    int goff = split*512 + ks*64 + pc*8;
#pragma unroll
    for(int j = 0; j < 2; ++j){
      int m = w*2 + j;                       // 0..7, 8 rows each
      gload16(Abase + (size_t)(m*8 + rsub)*8192 + goff, &A[m*512]);
      gload16(Bbase + (size_t)(m*8 + rsub)*8192 + goff, &Bs[m*512]);
    }
    __syncthreads();
#pragma unroll
    for(int kk = 0; kk < 2; ++kk){
      int g = kk*4 + (lane >> 4);
      int ra = w*16 + (lane & 15);
      short8 af = *(const short8*)&A[ra*64 + (g ^ (ra & 7))*8];
#pragma unroll
      for(int n4 = 0; n4 < 4; ++n4){
        int rb = n4*16 + (lane & 15);
        short8 bf = *(const short8*)&Bs[rb*64 + (g ^ (rb & 7))*8];
        acc[n4] = __builtin_amdgcn_mfma_f32_16x16x32_bf16(af, bf, acc[n4], 0,0,0);
      }
    }
    __syncthreads();
  }
  float* dst = ctxp + ((size_t)(bh*16 + split))*4096;
#pragma unroll
  for(int n4 = 0; n4 < 4; ++n4)
#pragma unroll
    for(int j = 0; j < 4; ++j){
      int d = w*16 + (lane >> 4)*4 + j, e = n4*16 + (lane & 15);
      dst[d*64 + e] = acc[n4][j];
    }
}

// ---------------- K3b: reduce ctx partials, scale by invZ, fold W_out: M2_b ---------------
__global__ void k_m2(const float* __restrict__ ctxp, const float* __restrict__ invZ,
                     const float* __restrict__ Wout, ushort* __restrict__ M2){
  __shared__ __align__(16) ushort ctxl[4096]; // chunked [g=e/8][d][8]
  int bh = blockIdx.x, b = bh >> 3, h = bh & 7;
  int t = threadIdx.x, lane = t & 63, w = t >> 6;  // 512 threads, 8 waves
  for(int i = t; i < 4096; i += 512){
    float s = 0.f;
    for(int sp = 0; sp < 16; ++sp) s += ctxp[((size_t)(bh*16 + sp))*4096 + i];
    int d = i >> 6, e = i & 63;
    s *= invZ[bh*64 + d];
    ctxl[(e >> 3)*512 + d*8 + (e & 7)] = f2bf(s);
  }
  __syncthreads();
  f32x4 acc[4][4] = {};
#pragma unroll
  for(int kk = 0; kk < 2; ++kk){
    int g = kk*4 + (lane >> 4);
    short8 bf[4];
#pragma unroll
    for(int n4 = 0; n4 < 4; ++n4)
      bf[n4] = *(const short8*)&ctxl[g*512 + (n4*16 + (lane & 15))*8];
    int e0 = (lane >> 4)*8 + kk*32;
#pragma unroll
    for(int m4 = 0; m4 < 4; ++m4){
      int o = w*64 + m4*16 + (lane & 15);
      const float* wp = Wout + (size_t)o*512 + h*64 + e0;
      float4 w0 = *(const float4*)(wp);
      float4 w1 = *(const float4*)(wp + 4);
      short8 af;
      af[0]=(short)f2bf(w0.x); af[1]=(short)f2bf(w0.y); af[2]=(short)f2bf(w0.z); af[3]=(short)f2bf(w0.w);
      af[4]=(short)f2bf(w1.x); af[5]=(short)f2bf(w1.y); af[6]=(short)f2bf(w1.z); af[7]=(short)f2bf(w1.w);
#pragma unroll
      for(int n4 = 0; n4 < 4; ++n4)
        acc[m4][n4] = __builtin_amdgcn_mfma_f32_16x16x32_bf16(af, bf[n4], acc[m4][n4], 0,0,0);
    }
  }
  ushort* dst = M2 + (size_t)b*512*512 + h*64;
#pragma unroll
  for(int m4 = 0; m4 < 4; ++m4)
#pragma unroll
    for(int n4 = 0; n4 < 4; ++n4)
#pragma unroll
      for(int j = 0; j < 4; ++j){
        int o = w*64 + m4*16 + (lane >> 4)*4 + j;
        int d = n4*16 + (lane & 15);
        dst[(size_t)o*512 + d] = f2bf(acc[m4][n4][j]);
      }
}

// ---------------- K4: out = rmsnorm(M2_b @ Q + b_out, g2), tall tile 512x64, K=512 --------
// LDS A row-major [512][32] (BK=32), chunk-XOR p ^ ((r>>1)&3); B [64][32] same.
__global__ __launch_bounds__(512,2) void k_out(const ushort* __restrict__ M2,
                                               const ushort* __restrict__ Qt,
                                               const float* __restrict__ bout,
                                               const float* __restrict__ g2,
                                               float* __restrict__ out){
  __shared__ __align__(16) ushort A[16384];  // 512 rows x 32 elems = 32 KiB
  __shared__ __align__(16) ushort Bs[2048];  // 64 rows x 32 elems
  __shared__ float colss[64];
  __shared__ float bo[512], gg[512];
  int bid = blockIdx.x;                      // 1024
  int wg = (bid & 7)*128 + (bid >> 3);       // XCD-contiguous per batch
  int b = wg >> 7, lb = wg & 127;
  int t = threadIdx.x, lane = t & 63, w = t >> 6;  // 8 waves
  bo[t & 511] = bout[t & 511];
  gg[t & 511] = g2[t & 511];
  if(t < 64) colss[t] = 0.f;
  const ushort* Abase = M2 + (size_t)b*262144;
  const ushort* Bbase = Qt + ((size_t)(b*8192 + lb*64))*512;
  int rsub = lane >> 2;                      // 0..15 (row within 16-row group)
  int pc   = (lane & 3) ^ ((lane >> 3) & 3); // pre-swizzled source chunk
  f32x4 acc[4][4] = {};
  for(int ks = 0; ks < 16; ++ks){
    int goff = ks*32 + pc*8;
#pragma unroll
    for(int j = 0; j < 4; ++j){
      int m = w*4 + j;                       // 0..31, 16 rows each
      gload16(Abase + (size_t)(m*16 + rsub)*512 + goff, &A[m*512]);
    }
    if(w >= 4){
      int m = w - 4;                         // 0..3, 16 rows each
      gload16(Bbase + (size_t)(m*16 + rsub)*512 + goff, &Bs[m*512]);
    }
    __syncthreads();
    int g = lane >> 4;
    short8 bf[4];
#pragma unroll
    for(int n4 = 0; n4 < 4; ++n4){
      int rb = n4*16 + (lane & 15);
      bf[n4] = *(const short8*)&Bs[rb*32 + (g ^ ((rb >> 1) & 3))*8];
    }
#pragma unroll
    for(int m4 = 0; m4 < 4; ++m4){
      int ra = w*64 + m4*16 + (lane & 15);
      short8 af = *(const short8*)&A[ra*32 + (g ^ ((ra >> 1) & 3))*8];
#pragma unroll
      for(int n4 = 0; n4 < 4; ++n4)
        acc[m4][n4] = __builtin_amdgcn_mfma_f32_16x16x32_bf16(af, bf[n4], acc[m4][n4], 0,0,0);
    }
    __syncthreads();
  }
  // bias + column sumsq
  float ps[4] = {0.f,0.f,0.f,0.f};
#pragma unroll
  for(int m4 = 0; m4 < 4; ++m4)
#pragma unroll
    for(int j = 0; j < 4; ++j){
      int o = w*64 + m4*16 + (lane >> 4)*4 + j;
      float bb = bo[o];
#pragma unroll
      for(int n4 = 0; n4 < 4; ++n4){
        float v = acc[m4][n4][j] + bb;
        acc[m4][n4][j] = v;
        ps[n4] += v*v;
      }
    }
#pragma unroll
  for(int n4 = 0; n4 < 4; ++n4) atomicAdd(&colss[n4*16 + (lane & 15)], ps[n4]);
  __syncthreads();
  float csc[4];
#pragma unroll
  for(int n4 = 0; n4 < 4; ++n4)
    csc[n4] = SQRT512 / fmaxf(sqrtf(colss[n4*16 + (lane & 15)]), 1e-12f);
  float* obase = out + ((size_t)b*512)*8192 + lb*64;
#pragma unroll
  for(int m4 = 0; m4 < 4; ++m4)
#pragma unroll
    for(int j = 0; j < 4; ++j){
      int o = w*64 + m4*16 + (lane >> 4)*4 + j;
      float gv = gg[o];
#pragma unroll
      for(int n4 = 0; n4 < 4; ++n4)
        obase[(size_t)o*8192 + n4*16 + (lane & 15)] = acc[m4][n4][j]*csc[n4]*gv;
    }
}

extern "C" void kernel_launch(void* const* d_in, const int* in_sizes, int n_in,
                              void* d_out, int out_size, void* d_ws, size_t ws_size,
                              hipStream_t stream){
  const float* x    = (const float*)d_in[0];
  const float* g1   = (const float*)d_in[1];
  const float* wqkv = (const float*)d_in[2];
  const float* wout = (const float*)d_in[3];
  const float* bout = (const float*)d_in[4];
  const float* g2   = (const float*)d_in[5];
  float* out = (float*)d_out;
  char* ws = (char*)d_ws;
  const size_t MB = 1024*1024;
  ushort* Qt      = (ushort*)(ws);              // 64 MiB  [b][l][512]
  ushort* EK      = (ushort*)(ws + 64*MB);      // 64 MiB  [b][512][l]
  ushort* W1      = (ushort*)(ws + 128*MB);     // 1.5 MiB
  float*  invnorm = (float*) (ws + 130*MB);     // 256 KiB
  float*  kpart   = (float*) (ws + 131*MB);     // 1 MiB [64 ct][4096 rows]
  float*  invZ    = (float*) (ws + 132*MB);     // 16 KiB
  float*  ctxp    = (float*) (ws + 133*MB);     // 16 MiB [64 bh][16][64][64]
  ushort* M2      = (ushort*)(ws + 149*MB);     // 4 MiB  [b][512][512]
  // d_out doubles as scratch until k_out: Xt in first half, V in second half
  ushort* Xt = (ushort*)d_out;
  ushort* V  = (ushort*)((char*)d_out + 64*MB);

  k_prep_w1<<<3072, 256, 0, stream>>>(wqkv, g1, W1);
  k_xt<<<dim3(128, 8), 256, 0, stream>>>(x, Xt, invnorm);
  k_qkv<<<6144, 256, 0, stream>>>(W1, Xt, invnorm, Qt, EK, V, kpart);
  k_invz<<<16, 256, 0, stream>>>(kpart, invZ);
  k_ctx<<<1024, 256, 0, stream>>>(EK, V, ctxp);
  k_m2<<<64, 512, 0, stream>>>(ctxp, invZ, wout, M2);
  k_out<<<1024, 512, 0, stream>>>(M2, Qt, bout, g2, out);
}